// Round 1
// baseline (7588.937 us; speedup 1.0000x reference)
//
#include <hip/hip_runtime.h>

// ---------------- problem constants ----------------
#define N_NODES 10000
#define T_STEPS 8
#define F_IN 4
#define H1 16
#define HEADS 4
#define H2 32
#define G 32
#define PW 16
#define E_EDGES 160000
#define ETOT (E_EDGES + N_NODES)   // edges + self loops = 170000

// ordered-uint key transform for float atomic max
__device__ __forceinline__ unsigned int fkey(float f) {
    unsigned int b = __float_as_uint(f);
    return (b & 0x80000000u) ? ~b : (b | 0x80000000u);
}
__device__ __forceinline__ float funkey(unsigned int k) {
    unsigned int b = (k & 0x80000000u) ? (k ^ 0x80000000u) : ~k;
    return __uint_as_float(b);
}
__device__ __forceinline__ float lrelu(float x) { return x > 0.f ? x : 0.2f * x; }
__device__ __forceinline__ float eluf(float x) { return x > 0.f ? x : (expf(x) - 1.f); }
__device__ __forceinline__ float sigmoidf(float x) { return 1.f / (1.f + expf(-x)); }

// ---------------- layer 1: projection + attention logits ----------------
// dyn: [N,T,F]; W1: [4,64]; as1/ad1: [4,16] flat 64
// writes z1: [T*N,64], asrc/adst: [T*N,4]
__global__ void k_l1_proj(const float* __restrict__ dyn, const float* __restrict__ W1,
                          const float* __restrict__ as1, const float* __restrict__ ad1,
                          float* __restrict__ z1, float* __restrict__ asrc,
                          float* __restrict__ adst) {
    __shared__ float sW[256], sAs[64], sAd[64];
    int tid = threadIdx.x;
    if (tid < 256) sW[tid] = W1[tid];
    if (tid < 64) { sAs[tid] = as1[tid]; sAd[tid] = ad1[tid]; }
    __syncthreads();
    int idx = blockIdx.x * blockDim.x + tid;
    if (idx >= T_STEPS * N_NODES) return;
    int t = idx / N_NODES, n = idx % N_NODES;
    const float4 xv = *reinterpret_cast<const float4*>(dyn + ((size_t)n * T_STEPS + t) * F_IN);
    float* zrow = z1 + (size_t)idx * 64;
    float a_s[HEADS] = {0.f, 0.f, 0.f, 0.f};
    float a_d[HEADS] = {0.f, 0.f, 0.f, 0.f};
#pragma unroll
    for (int j = 0; j < 64; ++j) {
        float z = xv.x * sW[j] + xv.y * sW[64 + j] + xv.z * sW[128 + j] + xv.w * sW[192 + j];
        zrow[j] = z;
        int h = j >> 4;
        a_s[h] += z * sAs[j];
        a_d[h] += z * sAd[j];
    }
#pragma unroll
    for (int h = 0; h < HEADS; ++h) {
        asrc[(size_t)idx * 4 + h] = a_s[h];
        adst[(size_t)idx * 4 + h] = a_d[h];
    }
}

// ---------------- layer 1 edge passes ----------------
__global__ void k_l1_max(const int* __restrict__ ei, const float* __restrict__ asrc,
                         const float* __restrict__ adst, unsigned int* __restrict__ mkey) {
    int idx = blockIdx.x * blockDim.x + threadIdx.x;
    if (idx >= T_STEPS * ETOT) return;
    int t = idx / ETOT, e = idx % ETOT;
    int src = (e < E_EDGES) ? ei[e] : (e - E_EDGES);
    int dst = (e < E_EDGES) ? ei[E_EDGES + e] : (e - E_EDGES);
    const float4 as = *reinterpret_cast<const float4*>(asrc + ((size_t)t * N_NODES + src) * 4);
    const float4 ad = *reinterpret_cast<const float4*>(adst + ((size_t)t * N_NODES + dst) * 4);
    unsigned int* mk = mkey + ((size_t)t * N_NODES + dst) * 4;
    atomicMax(mk + 0, fkey(lrelu(as.x + ad.x)));
    atomicMax(mk + 1, fkey(lrelu(as.y + ad.y)));
    atomicMax(mk + 2, fkey(lrelu(as.z + ad.z)));
    atomicMax(mk + 3, fkey(lrelu(as.w + ad.w)));
}

__global__ void k_l1_sum(const int* __restrict__ ei, const float* __restrict__ asrc,
                         const float* __restrict__ adst, const unsigned int* __restrict__ mkey,
                         float* __restrict__ ssum) {
    int idx = blockIdx.x * blockDim.x + threadIdx.x;
    if (idx >= T_STEPS * ETOT) return;
    int t = idx / ETOT, e = idx % ETOT;
    int src = (e < E_EDGES) ? ei[e] : (e - E_EDGES);
    int dst = (e < E_EDGES) ? ei[E_EDGES + e] : (e - E_EDGES);
    const float4 as = *reinterpret_cast<const float4*>(asrc + ((size_t)t * N_NODES + src) * 4);
    const float4 ad = *reinterpret_cast<const float4*>(adst + ((size_t)t * N_NODES + dst) * 4);
    size_t db = ((size_t)t * N_NODES + dst) * 4;
    atomicAdd(ssum + db + 0, expf(lrelu(as.x + ad.x) - funkey(mkey[db + 0])));
    atomicAdd(ssum + db + 1, expf(lrelu(as.y + ad.y) - funkey(mkey[db + 1])));
    atomicAdd(ssum + db + 2, expf(lrelu(as.z + ad.z) - funkey(mkey[db + 2])));
    atomicAdd(ssum + db + 3, expf(lrelu(as.w + ad.w) - funkey(mkey[db + 3])));
}

__global__ void k_l1_msg(const int* __restrict__ ei, const float* __restrict__ asrc,
                         const float* __restrict__ adst, const unsigned int* __restrict__ mkey,
                         const float* __restrict__ ssum, const float* __restrict__ z1,
                         float* __restrict__ out1) {
    int idx = blockIdx.x * blockDim.x + threadIdx.x;
    if (idx >= T_STEPS * ETOT) return;
    int t = idx / ETOT, e = idx % ETOT;
    int src = (e < E_EDGES) ? ei[e] : (e - E_EDGES);
    int dst = (e < E_EDGES) ? ei[E_EDGES + e] : (e - E_EDGES);
    const float4 as = *reinterpret_cast<const float4*>(asrc + ((size_t)t * N_NODES + src) * 4);
    const float4 ad = *reinterpret_cast<const float4*>(adst + ((size_t)t * N_NODES + dst) * 4);
    size_t db = ((size_t)t * N_NODES + dst) * 4;
    float att[4];
    att[0] = expf(lrelu(as.x + ad.x) - funkey(mkey[db + 0])) / ssum[db + 0];
    att[1] = expf(lrelu(as.y + ad.y) - funkey(mkey[db + 1])) / ssum[db + 1];
    att[2] = expf(lrelu(as.z + ad.z) - funkey(mkey[db + 2])) / ssum[db + 2];
    att[3] = expf(lrelu(as.w + ad.w) - funkey(mkey[db + 3])) / ssum[db + 3];
    const float* zs = z1 + ((size_t)t * N_NODES + src) * 64;
    float* od = out1 + ((size_t)t * N_NODES + dst) * 64;
#pragma unroll
    for (int q = 0; q < 16; ++q) {
        float4 zv = *reinterpret_cast<const float4*>(zs + q * 4);
        float a = att[q >> 2];
        atomicAdd(od + q * 4 + 0, zv.x * a);
        atomicAdd(od + q * 4 + 1, zv.y * a);
        atomicAdd(od + q * 4 + 2, zv.z * a);
        atomicAdd(od + q * 4 + 3, zv.w * a);
    }
}

__global__ void k_l1_post(float* __restrict__ out1, const float* __restrict__ b1) {
    int idx = blockIdx.x * blockDim.x + threadIdx.x;
    if (idx >= T_STEPS * N_NODES * 64) return;
    out1[idx] = eluf(out1[idx] + b1[idx & 63]);
}

// ---------------- layer 2: projection + attention logits ----------------
__global__ void k_l2_proj(const float* __restrict__ x, const float* __restrict__ W2,
                          const float* __restrict__ as2, const float* __restrict__ ad2,
                          float* __restrict__ z2, float* __restrict__ asrc,
                          float* __restrict__ adst) {
    __shared__ float sW[64 * 32];
    __shared__ float sAs[32], sAd[32];
    for (int i = threadIdx.x; i < 64 * 32; i += blockDim.x) sW[i] = W2[i];
    if (threadIdx.x < 32) { sAs[threadIdx.x] = as2[threadIdx.x]; sAd[threadIdx.x] = ad2[threadIdx.x]; }
    __syncthreads();
    int idx = blockIdx.x * blockDim.x + threadIdx.x;
    if (idx >= T_STEPS * N_NODES) return;
    const float* xr = x + (size_t)idx * 64;
    float z[32];
#pragma unroll
    for (int k = 0; k < 32; ++k) z[k] = 0.f;
    for (int j = 0; j < 64; ++j) {
        float xj = xr[j];
#pragma unroll
        for (int k = 0; k < 32; ++k) z[k] += xj * sW[j * 32 + k];
    }
    float s_ = 0.f, d_ = 0.f;
    float* zr = z2 + (size_t)idx * 32;
#pragma unroll
    for (int k = 0; k < 32; ++k) {
        zr[k] = z[k];
        s_ += z[k] * sAs[k];
        d_ += z[k] * sAd[k];
    }
    asrc[idx] = s_;
    adst[idx] = d_;
}

// ---------------- layer 2 edge passes (single head) ----------------
__global__ void k_l2_max(const int* __restrict__ ei, const float* __restrict__ asrc,
                         const float* __restrict__ adst, unsigned int* __restrict__ mkey) {
    int idx = blockIdx.x * blockDim.x + threadIdx.x;
    if (idx >= T_STEPS * ETOT) return;
    int t = idx / ETOT, e = idx % ETOT;
    int src = (e < E_EDGES) ? ei[e] : (e - E_EDGES);
    int dst = (e < E_EDGES) ? ei[E_EDGES + e] : (e - E_EDGES);
    float v = lrelu(asrc[(size_t)t * N_NODES + src] + adst[(size_t)t * N_NODES + dst]);
    atomicMax(mkey + (size_t)t * N_NODES + dst, fkey(v));
}

__global__ void k_l2_sum(const int* __restrict__ ei, const float* __restrict__ asrc,
                         const float* __restrict__ adst, const unsigned int* __restrict__ mkey,
                         float* __restrict__ ssum) {
    int idx = blockIdx.x * blockDim.x + threadIdx.x;
    if (idx >= T_STEPS * ETOT) return;
    int t = idx / ETOT, e = idx % ETOT;
    int src = (e < E_EDGES) ? ei[e] : (e - E_EDGES);
    int dst = (e < E_EDGES) ? ei[E_EDGES + e] : (e - E_EDGES);
    size_t db = (size_t)t * N_NODES + dst;
    float v = lrelu(asrc[(size_t)t * N_NODES + src] + adst[db]);
    atomicAdd(ssum + db, expf(v - funkey(mkey[db])));
}

__global__ void k_l2_msg(const int* __restrict__ ei, const float* __restrict__ asrc,
                         const float* __restrict__ adst, const unsigned int* __restrict__ mkey,
                         const float* __restrict__ ssum, const float* __restrict__ z2,
                         float* __restrict__ out2) {
    int idx = blockIdx.x * blockDim.x + threadIdx.x;
    if (idx >= T_STEPS * ETOT) return;
    int t = idx / ETOT, e = idx % ETOT;
    int src = (e < E_EDGES) ? ei[e] : (e - E_EDGES);
    int dst = (e < E_EDGES) ? ei[E_EDGES + e] : (e - E_EDGES);
    size_t db = (size_t)t * N_NODES + dst;
    float v = lrelu(asrc[(size_t)t * N_NODES + src] + adst[db]);
    float att = expf(v - funkey(mkey[db])) / ssum[db];
    const float* zs = z2 + ((size_t)t * N_NODES + src) * 32;
    float* od = out2 + db * 32;
#pragma unroll
    for (int q = 0; q < 8; ++q) {
        float4 zv = *reinterpret_cast<const float4*>(zs + q * 4);
        atomicAdd(od + q * 4 + 0, zv.x * att);
        atomicAdd(od + q * 4 + 1, zv.y * att);
        atomicAdd(od + q * 4 + 2, zv.z * att);
        atomicAdd(od + q * 4 + 3, zv.w * att);
    }
}

__global__ void k_l2_post(float* __restrict__ out2, const float* __restrict__ b2) {
    int idx = blockIdx.x * blockDim.x + threadIdx.x;
    if (idx >= T_STEPS * N_NODES * 32) return;
    out2[idx] = eluf(out2[idx] + b2[idx & 31]);
}

// ---------------- mean over nodes: cur_h [T,32] ----------------
__global__ void k_mean(const float* __restrict__ out2, float* __restrict__ cur_h) {
    int t = blockIdx.x;
    float acc[32];
#pragma unroll
    for (int c = 0; c < 32; ++c) acc[c] = 0.f;
    for (int n = threadIdx.x; n < N_NODES; n += blockDim.x) {
        const float* r = out2 + ((size_t)t * N_NODES + n) * 32;
#pragma unroll
        for (int c = 0; c < 32; ++c) acc[c] += r[c];
    }
    __shared__ float red[256];
    for (int c = 0; c < 32; ++c) {
        red[threadIdx.x] = acc[c];
        __syncthreads();
        for (int s = 128; s > 0; s >>= 1) {
            if (threadIdx.x < s) red[threadIdx.x] += red[threadIdx.x + s];
            __syncthreads();
        }
        if (threadIdx.x == 0) cur_h[t * 32 + c] = red[0] / (float)N_NODES;
        __syncthreads();
    }
}

// ---------------- GRU + heads + SIR rollout (single block, 128 threads) ----------------
__global__ void k_head(const float* __restrict__ cur_h, const float* __restrict__ h0,
                       const float* __restrict__ W_ih, const float* __restrict__ W_hh,
                       const float* __restrict__ b_ih, const float* __restrict__ b_hh,
                       const float* __restrict__ Wi, const float* __restrict__ bi,
                       const float* __restrict__ Wr, const float* __restrict__ br,
                       const float* __restrict__ Ws, const float* __restrict__ bs,
                       const float* __restrict__ cI, const float* __restrict__ cR,
                       const float* __restrict__ Nptr, const float* __restrict__ Ivec,
                       const float* __restrict__ Rvec, float* __restrict__ out) {
    __shared__ float h[32], gi[96], gh[96], hnew[32], hs[T_STEPS * 32], sirv[16];
    int j = threadIdx.x;
    if (j < 32) h[j] = h0[j];
    __syncthreads();
    for (int t = 0; t < T_STEPS; ++t) {
        if (j < 96) {
            float accI = b_ih[j], accH = b_hh[j];
            const float* xt = cur_h + t * 32;
            for (int k = 0; k < 32; ++k) {
                accI += W_ih[j * 32 + k] * xt[k];
                accH += W_hh[j * 32 + k] * h[k];
            }
            gi[j] = accI;
            gh[j] = accH;
        }
        __syncthreads();
        if (j < 32) {
            float r = sigmoidf(gi[j] + gh[j]);
            float zg = sigmoidf(gi[32 + j] + gh[32 + j]);
            float ng = tanhf(gi[64 + j] + r * gh[64 + j]);
            hnew[j] = (1.f - zg) * ng + zg * h[j];
        }
        __syncthreads();
        if (j < 32) {
            h[j] = hnew[j];
            hs[t * 32 + j] = hnew[j];
        }
        __syncthreads();
    }
    if (j < 32) out[512 + j] = h[j];  // h_final
    // new_I / new_R: j in [0,128) -> (t,p)
    {
        int t = j >> 4, p = j & 15;
        float accI = bi[p], accR = br[p];
        for (int k = 0; k < 34; ++k) {
            float hck = (k < 32) ? hs[t * 32 + k] : (k == 32 ? cI[t] : cR[t]);
            accI += hck * Wi[p * 34 + k];
            accR += hck * Wr[p * 34 + k];
        }
        out[j] = accI;
        out[128 + j] = accR;
    }
    if (j < 16) {
        int t = j >> 1, q = j & 1;
        float acc = bs[q];
        for (int k = 0; k < 34; ++k) {
            float hck = (k < 32) ? hs[t * 32 + k] : (k == 32 ? cI[t] : cR[t]);
            acc += hck * Ws[q * 34 + k];
        }
        sirv[j] = acc;
    }
    __syncthreads();
    if (j < 8) {
        int t = j;
        float alpha = sigmoidf(sirv[2 * t]);
        float beta = sigmoidf(sirv[2 * t + 1]);
        float Np = Nptr[0];
        float lI = Ivec[t], lR = Rvec[t];
        for (int p = 0; p < PW; ++p) {
            float lS = Np - lI - lR;
            float dI = alpha * lI * (lS / Np) - beta * lI;
            float dR = beta * lI;
            out[256 + t * 16 + p] = dI;
            out[384 + t * 16 + p] = dR;
            lI += dI;
            lR += dR;
        }
    }
}

extern "C" void kernel_launch(void* const* d_in, const int* in_sizes, int n_in,
                              void* d_out, int out_size, void* d_ws, size_t ws_size,
                              hipStream_t stream) {
    const float* dyn = (const float*)d_in[0];
    const float* cI = (const float*)d_in[1];
    const float* cR = (const float*)d_in[2];
    const float* Nptr = (const float*)d_in[3];
    const float* Ivec = (const float*)d_in[4];
    const float* Rvec = (const float*)d_in[5];
    const int* ei = (const int*)d_in[6];
    const float* h0 = (const float*)d_in[7];
    const float* W1 = (const float*)d_in[8];
    const float* as1 = (const float*)d_in[9];
    const float* ad1 = (const float*)d_in[10];
    const float* b1 = (const float*)d_in[11];
    const float* W2 = (const float*)d_in[12];
    const float* as2 = (const float*)d_in[13];
    const float* ad2 = (const float*)d_in[14];
    const float* b2 = (const float*)d_in[15];
    const float* W_ih = (const float*)d_in[16];
    const float* W_hh = (const float*)d_in[17];
    const float* b_ih = (const float*)d_in[18];
    const float* b_hh = (const float*)d_in[19];
    const float* Wi = (const float*)d_in[20];
    const float* bi = (const float*)d_in[21];
    const float* Wr = (const float*)d_in[22];
    const float* br = (const float*)d_in[23];
    const float* Ws = (const float*)d_in[24];
    const float* bs = (const float*)d_in[25];
    float* out = (float*)d_out;

    // workspace layout (bytes, 256-aligned) — total ~68 MB
    char* ws = (char*)d_ws;
    size_t off = 0;
    auto alloc = [&](size_t bytes) {
        void* p = ws + off;
        off += (bytes + 255) & ~(size_t)255;
        return p;
    };
    const size_t TN = (size_t)T_STEPS * N_NODES;
    float* z1 = (float*)alloc(TN * 64 * 4);
    float* asrc1 = (float*)alloc(TN * 4 * 4);
    float* adst1 = (float*)alloc(TN * 4 * 4);
    unsigned int* m1 = (unsigned int*)alloc(TN * 4 * 4);
    float* s1 = (float*)alloc(TN * 4 * 4);
    float* out1 = (float*)alloc(TN * 64 * 4);
    float* z2 = (float*)alloc(TN * 32 * 4);
    float* asrc2 = (float*)alloc(TN * 4);
    float* adst2 = (float*)alloc(TN * 4);
    unsigned int* m2 = (unsigned int*)alloc(TN * 4);
    float* s2 = (float*)alloc(TN * 4);
    float* out2 = (float*)alloc(TN * 32 * 4);
    float* cur_h = (float*)alloc(T_STEPS * 32 * 4);
    (void)ws_size;
    (void)in_sizes;
    (void)n_in;
    (void)out_size;

    // zero accumulators (mkey=0 is the minimum ordered key)
    hipMemsetAsync(m1, 0, TN * 4 * 4, stream);
    hipMemsetAsync(s1, 0, TN * 4 * 4, stream);
    hipMemsetAsync(out1, 0, TN * 64 * 4, stream);
    hipMemsetAsync(m2, 0, TN * 4, stream);
    hipMemsetAsync(s2, 0, TN * 4, stream);
    hipMemsetAsync(out2, 0, TN * 32 * 4, stream);

    const int BT = 256;
    int gNode = (int)((TN + BT - 1) / BT);                       // 313
    int gEdge = (int)(((size_t)T_STEPS * ETOT + BT - 1) / BT);   // 5313
    int gE1 = (int)((TN * 64 + BT - 1) / BT);
    int gE2 = (int)((TN * 32 + BT - 1) / BT);

    k_l1_proj<<<gNode, BT, 0, stream>>>(dyn, W1, as1, ad1, z1, asrc1, adst1);
    k_l1_max<<<gEdge, BT, 0, stream>>>(ei, asrc1, adst1, m1);
    k_l1_sum<<<gEdge, BT, 0, stream>>>(ei, asrc1, adst1, m1, s1);
    k_l1_msg<<<gEdge, BT, 0, stream>>>(ei, asrc1, adst1, m1, s1, z1, out1);
    k_l1_post<<<gE1, BT, 0, stream>>>(out1, b1);

    k_l2_proj<<<gNode, BT, 0, stream>>>(out1, W2, as2, ad2, z2, asrc2, adst2);
    k_l2_max<<<gEdge, BT, 0, stream>>>(ei, asrc2, adst2, m2);
    k_l2_sum<<<gEdge, BT, 0, stream>>>(ei, asrc2, adst2, m2, s2);
    k_l2_msg<<<gEdge, BT, 0, stream>>>(ei, asrc2, adst2, m2, s2, z2, out2);
    k_l2_post<<<gE2, BT, 0, stream>>>(out2, b2);

    k_mean<<<T_STEPS, BT, 0, stream>>>(out2, cur_h);
    k_head<<<1, 128, 0, stream>>>(cur_h, h0, W_ih, W_hh, b_ih, b_hh, Wi, bi, Wr, br, Ws, bs,
                                  cI, cR, Nptr, Ivec, Rvec, out);
}

// Round 2
// 446.826 us; speedup vs baseline: 16.9841x; 16.9841x over previous
//
#include <hip/hip_runtime.h>

// ---------------- problem constants ----------------
#define N_NODES 10000
#define T_STEPS 8
#define F_IN 4
#define H1 16
#define HEADS 4
#define H2 32
#define G 32
#define PW 16
#define E_EDGES 160000
#define ETOT (E_EDGES + N_NODES)   // edges + self loops = 170000

__device__ __forceinline__ float lrelu(float x) { return x > 0.f ? x : 0.2f * x; }
__device__ __forceinline__ float eluf(float x) { return x > 0.f ? x : (expf(x) - 1.f); }
__device__ __forceinline__ float sigmoidf(float x) { return 1.f / (1.f + expf(-x)); }
__device__ __forceinline__ float wmaxf(float v) {
#pragma unroll
    for (int o = 32; o; o >>= 1) v = fmaxf(v, __shfl_xor(v, o));
    return v;
}
__device__ __forceinline__ float wsumf(float v) {
#pragma unroll
    for (int o = 32; o; o >>= 1) v += __shfl_xor(v, o);
    return v;
}

// ---------------- CSR build (counting sort by dst) ----------------
__global__ void k_count(const int* __restrict__ ei, int* __restrict__ cnt) {
    int idx = blockIdx.x * blockDim.x + threadIdx.x;
    if (idx >= ETOT) return;
    int dst = (idx < E_EDGES) ? ei[E_EDGES + idx] : (idx - E_EDGES);
    atomicAdd(&cnt[dst], 1);
}

// single block, 256 threads: exclusive scan of cnt[0..N) -> rowptr, cursor
__global__ void k_scan(const int* __restrict__ cnt, int* __restrict__ rowptr,
                       int* __restrict__ cursor) {
    __shared__ int ssum[256];
    const int CH = (N_NODES + 255) / 256;  // 40
    int tid = threadIdx.x;
    int base = tid * CH;
    int loc = 0;
    for (int i = 0; i < CH; ++i) {
        int idx = base + i;
        if (idx < N_NODES) loc += cnt[idx];
    }
    ssum[tid] = loc;
    __syncthreads();
    for (int st = 1; st < 256; st <<= 1) {
        int v = (tid >= st) ? ssum[tid - st] : 0;
        __syncthreads();
        ssum[tid] += v;
        __syncthreads();
    }
    int run = ssum[tid] - loc;  // exclusive
    for (int i = 0; i < CH; ++i) {
        int idx = base + i;
        if (idx < N_NODES) {
            rowptr[idx] = run;
            cursor[idx] = run;
            run += cnt[idx];
        }
    }
    if (tid == 255) rowptr[N_NODES] = ssum[255];
}

__global__ void k_scatter(const int* __restrict__ ei, int* __restrict__ cursor,
                          int* __restrict__ colsrc) {
    int idx = blockIdx.x * blockDim.x + threadIdx.x;
    if (idx >= ETOT) return;
    int src = (idx < E_EDGES) ? ei[idx] : (idx - E_EDGES);
    int dst = (idx < E_EDGES) ? ei[E_EDGES + idx] : (idx - E_EDGES);
    int pos = atomicAdd(&cursor[dst], 1);
    colsrc[pos] = src;
}

// ---------------- layer 1: projection + attention logits ----------------
__global__ void k_l1_proj(const float* __restrict__ dyn, const float* __restrict__ W1,
                          const float* __restrict__ as1, const float* __restrict__ ad1,
                          float* __restrict__ z1, float* __restrict__ asrc,
                          float* __restrict__ adst) {
    __shared__ float sW[256], sAs[64], sAd[64];
    int tid = threadIdx.x;
    if (tid < 256) sW[tid] = W1[tid];
    if (tid < 64) { sAs[tid] = as1[tid]; sAd[tid] = ad1[tid]; }
    __syncthreads();
    int idx = blockIdx.x * blockDim.x + tid;
    if (idx >= T_STEPS * N_NODES) return;
    int t = idx / N_NODES, n = idx % N_NODES;
    const float4 xv = *reinterpret_cast<const float4*>(dyn + ((size_t)n * T_STEPS + t) * F_IN);
    float* zrow = z1 + (size_t)idx * 64;
    float a_s[HEADS] = {0.f, 0.f, 0.f, 0.f};
    float a_d[HEADS] = {0.f, 0.f, 0.f, 0.f};
#pragma unroll
    for (int j = 0; j < 64; ++j) {
        float z = xv.x * sW[j] + xv.y * sW[64 + j] + xv.z * sW[128 + j] + xv.w * sW[192 + j];
        zrow[j] = z;
        int h = j >> 4;
        a_s[h] += z * sAs[j];
        a_d[h] += z * sAd[j];
    }
#pragma unroll
    for (int h = 0; h < HEADS; ++h) {
        asrc[(size_t)idx * 4 + h] = a_s[h];
        adst[(size_t)idx * 4 + h] = a_d[h];
    }
}

// ---------------- layer 1 gather: one wave per (n,t), online softmax ----------------
// lanes own 64 output channels; edges processed in chunks of 64 (one per lane).
__global__ void k_l1_gather(const int* __restrict__ rowptr, const int* __restrict__ colsrc,
                            const float* __restrict__ asrc, const float* __restrict__ adst,
                            const float* __restrict__ z1, const float* __restrict__ b1,
                            float* __restrict__ out1) {
    int lane = threadIdx.x & 63;
    int wid = (blockIdx.x * blockDim.x + threadIdx.x) >> 6;
    if (wid >= N_NODES * T_STEPS) return;
    int n = wid >> 3, t = wid & 7;
    int beg = rowptr[n];
    int deg = rowptr[n + 1] - beg;
    const float4 ad = *reinterpret_cast<const float4*>(adst + ((size_t)t * N_NODES + n) * 4);
    int h = lane >> 4;
    float m0 = -1e30f, m1 = -1e30f, m2 = -1e30f, m3 = -1e30f;
    float s0 = 0.f, s1 = 0.f, s2 = 0.f, s3 = 0.f;
    float acc = 0.f;
    for (int base = 0; base < deg; base += 64) {
        int rem = deg - base;
        int cn = rem < 64 ? rem : 64;
        int src = 0;
        float l0 = -1e30f, l1 = -1e30f, l2 = -1e30f, l3 = -1e30f;
        if (lane < cn) {
            src = colsrc[beg + base + lane];
            const float4 as = *reinterpret_cast<const float4*>(asrc + ((size_t)t * N_NODES + src) * 4);
            l0 = lrelu(as.x + ad.x);
            l1 = lrelu(as.y + ad.y);
            l2 = lrelu(as.z + ad.z);
            l3 = lrelu(as.w + ad.w);
        }
        float nm0 = fmaxf(m0, wmaxf(l0)), nm1 = fmaxf(m1, wmaxf(l1));
        float nm2 = fmaxf(m2, wmaxf(l2)), nm3 = fmaxf(m3, wmaxf(l3));
        float f0 = expf(m0 - nm0), f1 = expf(m1 - nm1), f2 = expf(m2 - nm2), f3 = expf(m3 - nm3);
        s0 *= f0; s1 *= f1; s2 *= f2; s3 *= f3;
        acc *= (h == 0) ? f0 : (h == 1) ? f1 : (h == 2) ? f2 : f3;
        float w0 = (lane < cn) ? expf(l0 - nm0) : 0.f;
        float w1 = (lane < cn) ? expf(l1 - nm1) : 0.f;
        float w2 = (lane < cn) ? expf(l2 - nm2) : 0.f;
        float w3 = (lane < cn) ? expf(l3 - nm3) : 0.f;
        s0 += wsumf(w0); s1 += wsumf(w1); s2 += wsumf(w2); s3 += wsumf(w3);
        m0 = nm0; m1 = nm1; m2 = nm2; m3 = nm3;
        for (int e = 0; e < cn; ++e) {
            int se = __shfl(src, e);
            float w0e = __shfl(w0, e), w1e = __shfl(w1, e), w2e = __shfl(w2, e), w3e = __shfl(w3, e);
            float we = (h == 0) ? w0e : (h == 1) ? w1e : (h == 2) ? w2e : w3e;
            acc += we * z1[((size_t)t * N_NODES + se) * 64 + lane];
        }
    }
    float sh = (h == 0) ? s0 : (h == 1) ? s1 : (h == 2) ? s2 : s3;
    out1[((size_t)t * N_NODES + n) * 64 + lane] = eluf(acc / sh + b1[lane]);
}

// ---------------- layer 2: projection + attention logits ----------------
__global__ void k_l2_proj(const float* __restrict__ x, const float* __restrict__ W2,
                          const float* __restrict__ as2, const float* __restrict__ ad2,
                          float* __restrict__ z2, float* __restrict__ asrc,
                          float* __restrict__ adst) {
    __shared__ float sW[64 * 32];
    __shared__ float sAs[32], sAd[32];
    for (int i = threadIdx.x; i < 64 * 32; i += blockDim.x) sW[i] = W2[i];
    if (threadIdx.x < 32) { sAs[threadIdx.x] = as2[threadIdx.x]; sAd[threadIdx.x] = ad2[threadIdx.x]; }
    __syncthreads();
    int idx = blockIdx.x * blockDim.x + threadIdx.x;
    if (idx >= T_STEPS * N_NODES) return;
    const float* xr = x + (size_t)idx * 64;
    float z[32];
#pragma unroll
    for (int k = 0; k < 32; ++k) z[k] = 0.f;
    for (int j = 0; j < 64; ++j) {
        float xj = xr[j];
#pragma unroll
        for (int k = 0; k < 32; ++k) z[k] += xj * sW[j * 32 + k];
    }
    float s_ = 0.f, d_ = 0.f;
    float* zr = z2 + (size_t)idx * 32;
#pragma unroll
    for (int k = 0; k < 32; ++k) {
        zr[k] = z[k];
        s_ += z[k] * sAs[k];
        d_ += z[k] * sAd[k];
    }
    asrc[idx] = s_;
    adst[idx] = d_;
}

// ---------------- layer 2 gather: one wave per (n,t), 1 head, 32 channels ----------------
// lanes 0-31 / 32-63 process even/odd edges in the accumulate loop, reduced at the end.
__global__ void k_l2_gather(const int* __restrict__ rowptr, const int* __restrict__ colsrc,
                            const float* __restrict__ asrc, const float* __restrict__ adst,
                            const float* __restrict__ z2, const float* __restrict__ b2,
                            float* __restrict__ out2) {
    int lane = threadIdx.x & 63;
    int wid = (blockIdx.x * blockDim.x + threadIdx.x) >> 6;
    if (wid >= N_NODES * T_STEPS) return;
    int n = wid >> 3, t = wid & 7;
    int beg = rowptr[n];
    int deg = rowptr[n + 1] - beg;
    float ad = adst[(size_t)t * N_NODES + n];
    int c = lane & 31, sub = lane >> 5;
    float m = -1e30f, s = 0.f, acc = 0.f;
    for (int base = 0; base < deg; base += 64) {
        int rem = deg - base;
        int cn = rem < 64 ? rem : 64;
        int src = 0;
        float lg = -1e30f;
        if (lane < cn) {
            src = colsrc[beg + base + lane];
            lg = lrelu(asrc[(size_t)t * N_NODES + src] + ad);
        }
        float nm = fmaxf(m, wmaxf(lg));
        float f = expf(m - nm);
        s *= f;
        acc *= f;
        float w = (lane < cn) ? expf(lg - nm) : 0.f;
        s += wsumf(w);
        m = nm;
        for (int e = 0; e < cn; e += 2) {
            int ee = e + sub;
            bool ok = ee < cn;
            int pick = ok ? ee : 0;
            int se = __shfl(src, pick);
            float we = __shfl(w, pick);
            if (ok) acc += we * z2[((size_t)t * N_NODES + se) * 32 + c];
        }
    }
    acc += __shfl_xor(acc, 32);
    if (lane < 32) out2[((size_t)t * N_NODES + n) * 32 + c] = eluf(acc / s + b2[c]);
}

// ---------------- mean over nodes: cur_h [T,32] ----------------
__global__ void k_mean(const float* __restrict__ out2, float* __restrict__ cur_h) {
    int t = blockIdx.x;
    float acc[32];
#pragma unroll
    for (int c = 0; c < 32; ++c) acc[c] = 0.f;
    for (int n = threadIdx.x; n < N_NODES; n += blockDim.x) {
        const float* r = out2 + ((size_t)t * N_NODES + n) * 32;
#pragma unroll
        for (int c = 0; c < 32; ++c) acc[c] += r[c];
    }
    __shared__ float red[256];
    for (int c = 0; c < 32; ++c) {
        red[threadIdx.x] = acc[c];
        __syncthreads();
        for (int s = 128; s > 0; s >>= 1) {
            if (threadIdx.x < s) red[threadIdx.x] += red[threadIdx.x + s];
            __syncthreads();
        }
        if (threadIdx.x == 0) cur_h[t * 32 + c] = red[0] / (float)N_NODES;
        __syncthreads();
    }
}

// ---------------- GRU + heads + SIR rollout (single block, 128 threads) ----------------
__global__ void k_head(const float* __restrict__ cur_h, const float* __restrict__ h0,
                       const float* __restrict__ W_ih, const float* __restrict__ W_hh,
                       const float* __restrict__ b_ih, const float* __restrict__ b_hh,
                       const float* __restrict__ Wi, const float* __restrict__ bi,
                       const float* __restrict__ Wr, const float* __restrict__ br,
                       const float* __restrict__ Ws, const float* __restrict__ bs,
                       const float* __restrict__ cI, const float* __restrict__ cR,
                       const float* __restrict__ Nptr, const float* __restrict__ Ivec,
                       const float* __restrict__ Rvec, float* __restrict__ out) {
    __shared__ float h[32], gi[96], gh[96], hnew[32], hs[T_STEPS * 32], sirv[16];
    int j = threadIdx.x;
    if (j < 32) h[j] = h0[j];
    __syncthreads();
    for (int t = 0; t < T_STEPS; ++t) {
        if (j < 96) {
            float accI = b_ih[j], accH = b_hh[j];
            const float* xt = cur_h + t * 32;
            for (int k = 0; k < 32; ++k) {
                accI += W_ih[j * 32 + k] * xt[k];
                accH += W_hh[j * 32 + k] * h[k];
            }
            gi[j] = accI;
            gh[j] = accH;
        }
        __syncthreads();
        if (j < 32) {
            float r = sigmoidf(gi[j] + gh[j]);
            float zg = sigmoidf(gi[32 + j] + gh[32 + j]);
            float ng = tanhf(gi[64 + j] + r * gh[64 + j]);
            hnew[j] = (1.f - zg) * ng + zg * h[j];
        }
        __syncthreads();
        if (j < 32) {
            h[j] = hnew[j];
            hs[t * 32 + j] = hnew[j];
        }
        __syncthreads();
    }
    if (j < 32) out[512 + j] = h[j];  // h_final
    {
        int t = j >> 4, p = j & 15;
        float accI = bi[p], accR = br[p];
        for (int k = 0; k < 34; ++k) {
            float hck = (k < 32) ? hs[t * 32 + k] : (k == 32 ? cI[t] : cR[t]);
            accI += hck * Wi[p * 34 + k];
            accR += hck * Wr[p * 34 + k];
        }
        out[j] = accI;
        out[128 + j] = accR;
    }
    if (j < 16) {
        int t = j >> 1, q = j & 1;
        float acc = bs[q];
        for (int k = 0; k < 34; ++k) {
            float hck = (k < 32) ? hs[t * 32 + k] : (k == 32 ? cI[t] : cR[t]);
            acc += hck * Ws[q * 34 + k];
        }
        sirv[j] = acc;
    }
    __syncthreads();
    if (j < 8) {
        int t = j;
        float alpha = sigmoidf(sirv[2 * t]);
        float beta = sigmoidf(sirv[2 * t + 1]);
        float Np = Nptr[0];
        float lI = Ivec[t], lR = Rvec[t];
        for (int p = 0; p < PW; ++p) {
            float lS = Np - lI - lR;
            float dI = alpha * lI * (lS / Np) - beta * lI;
            float dR = beta * lI;
            out[256 + t * 16 + p] = dI;
            out[384 + t * 16 + p] = dR;
            lI += dI;
            lR += dR;
        }
    }
}

extern "C" void kernel_launch(void* const* d_in, const int* in_sizes, int n_in,
                              void* d_out, int out_size, void* d_ws, size_t ws_size,
                              hipStream_t stream) {
    const float* dyn = (const float*)d_in[0];
    const float* cI = (const float*)d_in[1];
    const float* cR = (const float*)d_in[2];
    const float* Nptr = (const float*)d_in[3];
    const float* Ivec = (const float*)d_in[4];
    const float* Rvec = (const float*)d_in[5];
    const int* ei = (const int*)d_in[6];
    const float* h0 = (const float*)d_in[7];
    const float* W1 = (const float*)d_in[8];
    const float* as1 = (const float*)d_in[9];
    const float* ad1 = (const float*)d_in[10];
    const float* b1 = (const float*)d_in[11];
    const float* W2 = (const float*)d_in[12];
    const float* as2 = (const float*)d_in[13];
    const float* ad2 = (const float*)d_in[14];
    const float* b2 = (const float*)d_in[15];
    const float* W_ih = (const float*)d_in[16];
    const float* W_hh = (const float*)d_in[17];
    const float* b_ih = (const float*)d_in[18];
    const float* b_hh = (const float*)d_in[19];
    const float* Wi = (const float*)d_in[20];
    const float* bi = (const float*)d_in[21];
    const float* Wr = (const float*)d_in[22];
    const float* br = (const float*)d_in[23];
    const float* Ws = (const float*)d_in[24];
    const float* bs = (const float*)d_in[25];
    float* out = (float*)d_out;

    char* ws = (char*)d_ws;
    size_t off = 0;
    auto alloc = [&](size_t bytes) {
        void* p = ws + off;
        off += (bytes + 255) & ~(size_t)255;
        return p;
    };
    const size_t TN = (size_t)T_STEPS * N_NODES;
    float* z1 = (float*)alloc(TN * 64 * 4);
    float* asrc1 = (float*)alloc(TN * 4 * 4);
    float* adst1 = (float*)alloc(TN * 4 * 4);
    float* out1 = (float*)alloc(TN * 64 * 4);
    float* z2 = (float*)alloc(TN * 32 * 4);
    float* asrc2 = (float*)alloc(TN * 4);
    float* adst2 = (float*)alloc(TN * 4);
    float* out2 = (float*)alloc(TN * 32 * 4);
    float* cur_h = (float*)alloc(T_STEPS * 32 * 4);
    int* cnt = (int*)alloc((N_NODES + 1) * 4);
    int* rowptr = (int*)alloc((N_NODES + 1) * 4);
    int* cursor = (int*)alloc(N_NODES * 4);
    int* colsrc = (int*)alloc((size_t)ETOT * 4);
    (void)ws_size; (void)in_sizes; (void)n_in; (void)out_size;

    const int BT = 256;
    hipMemsetAsync(cnt, 0, (N_NODES + 1) * 4, stream);
    int gEdgeFlat = (ETOT + BT - 1) / BT;
    k_count<<<gEdgeFlat, BT, 0, stream>>>(ei, cnt);
    k_scan<<<1, 256, 0, stream>>>(cnt, rowptr, cursor);
    k_scatter<<<gEdgeFlat, BT, 0, stream>>>(ei, cursor, colsrc);

    int gNode = (int)((TN + BT - 1) / BT);        // 313
    int gWave = (int)((TN * 64 + BT - 1) / BT);   // one wave per (n,t): 20000 blocks

    k_l1_proj<<<gNode, BT, 0, stream>>>(dyn, W1, as1, ad1, z1, asrc1, adst1);
    k_l1_gather<<<gWave, BT, 0, stream>>>(rowptr, colsrc, asrc1, adst1, z1, b1, out1);

    k_l2_proj<<<gNode, BT, 0, stream>>>(out1, W2, as2, ad2, z2, asrc2, adst2);
    k_l2_gather<<<gWave, BT, 0, stream>>>(rowptr, colsrc, asrc2, adst2, z2, b2, out2);

    k_mean<<<T_STEPS, BT, 0, stream>>>(out2, cur_h);
    k_head<<<1, 128, 0, stream>>>(cur_h, h0, W_ih, W_hh, b_ih, b_hh, Wi, bi, Wr, br, Ws, bs,
                                  cI, cR, Nptr, Ivec, Rvec, out);
}